// Round 12
// baseline (337.524 us; speedup 1.0000x reference)
//
#include <hip/hip_runtime.h>
#include <hip/hip_bf16.h>
#include <math.h>

// Geometry (fixed):
//   x: (N=4, C=64, D=32, H=64, W=64); S = 131072 = G*P, G=512, P=256
//   W1 (128,64) b1(128) | W2 (512,512) b2(512) | W3 (256,256) b3(256) | W4 (64,128) b4(64)
// Blocked index: g=(d>>2)*64+(h>>3)*8+(w>>3); p=(d&3)*64+(h&7)*8+(w&7)
//
// Pipeline (batched; cnt=4 if ws fits):
//   detect -> stats+prepW -> red+prep ->
//   fc1:  per-g GEMM, LN folded, sigmoid-GELU -> Au[c][g][p] (buf2), Bv[g][c][p] (d_out n)
//   k_tv: vmix (Bv -> T_V, buf3)  PARALLEL WITH  transA (Au -> At', buf1)
//   umix: At' -> T_U (buf2)
//   fc2:  LDS-free GEMM from T_U/T_V -> out

#define S_PER_N 131072
#define CNT_PER_N 8388608.0f

typedef __attribute__((ext_vector_type(8))) short bf16x8;
typedef __attribute__((ext_vector_type(4))) float f32x4;

__device__ __forceinline__ float b2f(unsigned short u) {
    return __uint_as_float(((unsigned int)u) << 16);
}
__device__ __forceinline__ unsigned short f2b(float f) {
    unsigned int i = __float_as_uint(f);
    unsigned int r = i + 0x7FFFu + ((i >> 16) & 1u);
    return (unsigned short)(r >> 16);
}
// pack 2 f32 -> 2 bf16 (RNE) in one instruction
__device__ __forceinline__ unsigned int pk2(float lo, float hi) {
    unsigned int r;
    asm("v_cvt_pk_bf16_f32 %0, %1, %2" : "=v"(r) : "v"(lo), "v"(hi));
    return r;
}
__device__ __forceinline__ float loadIn(const void* p, long i, bool f32) {
    return f32 ? ((const float*)p)[i] : b2f(((const unsigned short*)p)[i]);
}
__device__ __forceinline__ void storeOut(void* p, long i, float v, bool f32) {
    if (f32) ((float*)p)[i] = v;
    else ((unsigned short*)p)[i] = f2b(v);
}
__device__ __forceinline__ void gld16(const unsigned short* g, unsigned short* l) {
    __builtin_amdgcn_global_load_lds(
        (const __attribute__((address_space(1))) void*)g,
        (__attribute__((address_space(3))) void*)l,
        16, 0, 0);
}
// GELU sigmoid/tanh form: x * sigmoid(1.595769x + 0.0713548x^3); max abs err ~3e-4
__device__ __forceinline__ float fast_gelu(float x) {
    const float x2 = x * x;
    const float c = -0.102944f * x2 - 2.3022081f;     // -2*log2(e)*(0.79788456 + 0.03567741 x^2)
    const float q = x * c;
    const float t = __builtin_amdgcn_rcpf(1.0f + __builtin_amdgcn_exp2f(q));
    return x * t;
}

// ---------------- dtype detect ----------------
__global__ void k_detect(const unsigned short* __restrict__ xw, float* __restrict__ flag) {
    __shared__ int sh[256];
    int tid = threadIdx.x;
    int sane = 0;
    for (int i = tid; i < 4096; i += 256) {
        int e = (xw[i] >> 7) & 0xFF;
        sane += (e >= 110 && e <= 130) ? 1 : 0;
    }
    sh[tid] = sane; __syncthreads();
    for (int off = 128; off; off >>= 1) {
        if (tid < off) sh[tid] += sh[tid + off];
        __syncthreads();
    }
    if (tid == 0) flag[0] = (sh[0] >= 3300) ? 0.0f : 1.0f;
}

// ---------------- LN stats (blocks 0..511) + prepW (blocks 512..1535) ----------------
__global__ __launch_bounds__(256) void k_stats_prepW(const void* __restrict__ xp,
                                                     const float* __restrict__ flag,
                                                     float* __restrict__ partials,
                                                     const void* __restrict__ W1,
                                                     const void* __restrict__ W2,
                                                     const void* __restrict__ W3,
                                                     const void* __restrict__ W4,
                                                     unsigned short* __restrict__ W1b,
                                                     unsigned short* __restrict__ W2b,
                                                     unsigned short* __restrict__ W3b,
                                                     unsigned short* __restrict__ W4b) {
    const bool f32 = flag[0] > 0.5f;
    if (blockIdx.x >= 512) {
        const int i = (blockIdx.x - 512) * 256 + threadIdx.x;
        if (i < 512 * 512) W2b[i] = f32 ? f2b(((const float*)W2)[i]) : ((const unsigned short*)W2)[i];
        if (i < 256 * 256) W3b[i] = f32 ? f2b(((const float*)W3)[i]) : ((const unsigned short*)W3)[i];
        if (i < 128 * 64)  W1b[i] = f32 ? f2b(((const float*)W1)[i]) : ((const unsigned short*)W1)[i];
        if (i < 64 * 128)  W4b[i] = f32 ? f2b(((const float*)W4)[i]) : ((const unsigned short*)W4)[i];
        return;
    }
    const int bid = blockIdx.x;
    const long base = (long)bid * 65536;
    float s = 0.0f, sq = 0.0f;
    if (f32) {
        const float4* xv = (const float4*)((const float*)xp + base);
        for (int it = 0; it < 64; ++it) {
            float4 v = xv[it * 256 + threadIdx.x];
            s  += v.x + v.y + v.z + v.w;
            sq += v.x*v.x + v.y*v.y + v.z*v.z + v.w*v.w;
        }
    } else {
        const uint4* xv = (const uint4*)((const unsigned short*)xp + base);
        for (int it = 0; it < 32; ++it) {
            uint4 v = xv[it * 256 + threadIdx.x];
            unsigned int ws4[4] = {v.x, v.y, v.z, v.w};
            #pragma unroll
            for (int q = 0; q < 4; ++q) {
                float f0 = b2f((unsigned short)(ws4[q] & 0xFFFFu));
                float f1 = b2f((unsigned short)(ws4[q] >> 16));
                s += f0 + f1;
                sq += f0 * f0 + f1 * f1;
            }
        }
    }
    __shared__ float ls[256], lq[256];
    ls[threadIdx.x] = s; lq[threadIdx.x] = sq;
    __syncthreads();
    for (int off = 128; off > 0; off >>= 1) {
        if (threadIdx.x < off) {
            ls[threadIdx.x] += ls[threadIdx.x + off];
            lq[threadIdx.x] += lq[threadIdx.x + off];
        }
        __syncthreads();
    }
    if (threadIdx.x == 0) {
        partials[bid * 2 + 0] = ls[0];
        partials[bid * 2 + 1] = lq[0];
    }
}

// ---------------- reduce partials -> stats, then ck (1 block, 128 thr) ----------------
__global__ void k_red_prep(const float* __restrict__ partials, float* __restrict__ stats,
                           const void* __restrict__ W1, const void* __restrict__ b1,
                           const float* __restrict__ flag, float* __restrict__ ck) {
    const int t = threadIdx.x;
    if (t < 4) {
        float s = 0.0f, sq = 0.0f;
        for (int i = 0; i < 128; ++i) {
            s  += partials[(t * 128 + i) * 2 + 0];
            sq += partials[(t * 128 + i) * 2 + 1];
        }
        stats[t * 2 + 0] = s;
        stats[t * 2 + 1] = sq;
    }
    __syncthreads();
    const bool f32 = flag[0] > 0.5f;
    float rs = 0.0f;
    for (int c = 0; c < 64; ++c) rs += loadIn(W1, (long)t * 64 + c, f32);
    const float bb = loadIn(b1, t, f32);
    for (int n = 0; n < 4; ++n) {
        const float mu   = stats[n * 2 + 0] * (1.0f / CNT_PER_N);
        const float m2   = stats[n * 2 + 1] * (1.0f / CNT_PER_N);
        const float rstd = rsqrtf(m2 - mu * mu + 1e-5f);
        ck[n * 128 + t] = bb - rstd * mu * rs;
    }
}

// ---------------- LDS swizzle helper ----------------
__device__ __forceinline__ bf16x8 fragLd(const unsigned short* lds, int r, int c) {
    return *(const bf16x8*)&lds[r * 64 + ((c ^ (r & 7)) << 3)];
}

// ---------------- fc1 (g-tile): D[p=256][j=128], K=64; LN folded, fast GELU ----------------
__global__ __launch_bounds__(256) void k_fc1_mfma(const void* __restrict__ xp,
                                                  const float* __restrict__ stats,
                                                  const float* __restrict__ ck,
                                                  const unsigned short* __restrict__ W1b,
                                                  const float* __restrict__ flag,
                                                  unsigned short* __restrict__ AuBase,
                                                  void* __restrict__ outBase, int nBase) {
    const bool f32 = flag[0] > 0.5f;
    __shared__ __align__(16) unsigned short Bs[256 * 64];   // X^T [p][c]
    const int nwg = gridDim.x;
    const int cpx = nwg >> 3;
    const int work = (blockIdx.x & 7) * cpx + (blockIdx.x >> 3);
    const int nl = work >> 9;
    const int n = nBase + nl;
    const int g = work & 511;
    const int d0 = (g >> 6) * 4, h0 = ((g >> 3) & 7) * 8, w0 = (g & 7) * 8;
    const int t = threadIdx.x;
    const int lane = t & 63, wid = t >> 6;
    const int waveP = wid * 64;
    const int lr = lane & 15, lk = lane >> 4;

    unsigned short* Au = AuBase + (size_t)nl * 8388608;
    unsigned short* Bv = (unsigned short*)((char*)outBase + (size_t)n * 8388608 * (f32 ? 4 : 2));

    {   // stage B: x g-block -> Bs[p][c]
        const int c0 = (t & 31) * 2;
        const int rdh = t >> 5;
        const long cbase = ((long)(n * 64 + c0)) << 17;
        const int ch = c0 >> 3, cof = c0 & 7;
        #pragma unroll
        for (int q = 0; q < 4; ++q) {
            const int dh = rdh * 4 + q;
            const int dp = dh >> 3, hp = dh & 7;
            const long sb = (long)(d0 + dp) * 4096 + (h0 + hp) * 64 + w0;
            const int pbase = dp * 64 + hp * 8;
            if (f32) {
                const float* r0 = (const float*)xp + cbase + sb;
                const float* r1 = r0 + S_PER_N;
                float4 a0 = *(const float4*)r0, a1 = *(const float4*)(r0 + 4);
                float4 b0 = *(const float4*)r1, b1v = *(const float4*)(r1 + 4);
                float ff0[8] = {a0.x, a0.y, a0.z, a0.w, a1.x, a1.y, a1.z, a1.w};
                float ff1[8] = {b0.x, b0.y, b0.z, b0.w, b1v.x, b1v.y, b1v.z, b1v.w};
                #pragma unroll
                for (int j = 0; j < 8; ++j) {
                    const int pj = pbase + j;
                    *(unsigned int*)&Bs[pj * 64 + ((ch ^ (pj & 7)) << 3) + cof] = pk2(ff0[j], ff1[j]);
                }
            } else {
                const unsigned short* r0 = (const unsigned short*)xp + cbase + sb;
                uint4 a = *(const uint4*)r0;
                uint4 b = *(const uint4*)(r0 + S_PER_N);
                const unsigned short* pa = (const unsigned short*)&a;
                const unsigned short* pb = (const unsigned short*)&b;
                #pragma unroll
                for (int j = 0; j < 8; ++j) {
                    const int pj = pbase + j;
                    unsigned int val = (unsigned int)pa[j] | ((unsigned int)pb[j] << 16);
                    *(unsigned int*)&Bs[pj * 64 + ((ch ^ (pj & 7)) << 3) + cof] = val;
                }
            }
        }
    }
    __syncthreads();

    const float mu   = stats[n * 2 + 0] * (1.0f / CNT_PER_N);
    const float m2   = stats[n * 2 + 1] * (1.0f / CNT_PER_N);
    const float rstd = rsqrtf(m2 - mu * mu + 1e-5f);

    #pragma unroll
    for (int half = 0; half < 2; ++half) {
        f32x4 zero = {0.f, 0.f, 0.f, 0.f};
        f32x4 acc[4][4];
        #pragma unroll
        for (int i = 0; i < 4; ++i)
            #pragma unroll
            for (int j = 0; j < 4; ++j) acc[i][j] = zero;

        #pragma unroll
        for (int kk = 0; kk < 2; ++kk) {
            bf16x8 bp[4], aj[4];
            #pragma unroll
            for (int f = 0; f < 4; ++f) {
                bp[f] = fragLd(Bs, waveP + f * 16 + lr, kk * 4 + lk);
                aj[f] = *(const bf16x8*)(W1b + (long)(half * 64 + f * 16 + lr) * 64 + (kk * 4 + lk) * 8);
            }
            #pragma unroll
            for (int fp = 0; fp < 4; ++fp)
                #pragma unroll
                for (int fj = 0; fj < 4; ++fj)
                    acc[fp][fj] = __builtin_amdgcn_mfma_f32_16x16x32_bf16(bp[fp], aj[fj], acc[fp][fj], 0, 0, 0);
        }

        #pragma unroll
        for (int fj = 0; fj < 4; ++fj) {
            const int j = half * 64 + fj * 16 + lr;
            const float ckj = ck[n * 128 + j];
            #pragma unroll
            for (int fp = 0; fp < 4; ++fp) {
                const int pb = waveP + fp * 16 + lk * 4;
                float gg[4];
                #pragma unroll
                for (int i = 0; i < 4; ++i)
                    gg[i] = fast_gelu(acc[fp][fj][i] * rstd + ckj);
                uint2 pk;
                pk.x = pk2(gg[0], gg[1]);
                pk.y = pk2(gg[2], gg[3]);
                if (half == 0) {
                    *(uint2*)&Au[(long)j * S_PER_N + g * 256 + pb] = pk;
                } else {
                    *(uint2*)&Bv[((long)g * 64 + (j - 64)) * 256 + pb] = pk;
                }
            }
        }
    }
}

// ---------------- k_tv: vmix (blocks 0..nV-1) PARALLEL WITH transA (rest) ----------------
// vmix: GEMM (global_load_lds staged), out T_V[(g*256+k)*64+c] in buf3
// transA: Au[c][g][p] -> At'[(p*64+c)][g] in buf1
__global__ __launch_bounds__(256) void k_tv(const unsigned short* __restrict__ AuBase,
                                            void* __restrict__ outBase,
                                            const unsigned short* __restrict__ W3b,
                                            const void* __restrict__ b3,
                                            const float* __restrict__ flag,
                                            unsigned short* __restrict__ AtBase,
                                            unsigned short* __restrict__ TVBase,
                                            int nBase, int nV) {
    __shared__ __align__(16) unsigned short smem[17408];
    const int t = threadIdx.x;

    if ((int)blockIdx.x < nV) {
        // ---- vmix body ----
        const bool f32 = flag[0] > 0.5f;
        unsigned short* As = smem;
        unsigned short* Bs = smem + 8192;
        unsigned short* Ot = smem;
        const int bid = blockIdx.x;
        const int nl = bid >> 9;
        const int n = nBase + nl;
        const int inner = bid & 511;
        const unsigned short* Bv = (const unsigned short*)((char*)outBase + (size_t)n * 8388608 * (f32 ? 4 : 2));
        unsigned short* TV = TVBase + (size_t)nl * 8388608;
        const int mTile = inner >> 8;
        const int nTile = inner & 255;
        const int m0 = mTile * 128;
        const int lane = t & 63, wid = t >> 6;
        const int waveM = (wid >> 1) * 64, waveN = (wid & 1) * 64;
        const int lr = lane & 15, lk = lane >> 4;
        const int rIn8 = lane >> 3;
        const int swzOff = ((lane & 7) ^ rIn8) << 3;

        f32x4 zero = {0.f, 0.f, 0.f, 0.f};
        f32x4 acc[4][4];
        #pragma unroll
        for (int i = 0; i < 4; ++i)
            #pragma unroll
            for (int j = 0; j < 4; ++j) acc[i][j] = zero;

        for (int kb = 0; kb < 256; kb += 64) {
            #pragma unroll
            for (int call = 0; call < 4; ++call) {
                const int rowBase = call * 32 + wid * 8;
                gld16(W3b + (long)(m0 + rowBase + rIn8) * 256 + kb + swzOff, As + rowBase * 64);
                gld16(Bv + (long)(nTile * 128 + rowBase + rIn8) * 256 + kb + swzOff, Bs + rowBase * 64);
            }
            __syncthreads();
            #pragma unroll
            for (int kk = 0; kk < 2; ++kk) {
                bf16x8 tok[4], wf[4];
                #pragma unroll
                for (int f = 0; f < 4; ++f) {
                    tok[f] = fragLd(Bs, waveN + f * 16 + lr, kk * 4 + lk);
                    wf[f]  = fragLd(As, waveM + f * 16 + lr, kk * 4 + lk);
                }
                #pragma unroll
                for (int fm = 0; fm < 4; ++fm)
                    #pragma unroll
                    for (int fn = 0; fn < 4; ++fn)
                        acc[fm][fn] = __builtin_amdgcn_mfma_f32_16x16x32_bf16(tok[fm], wf[fn], acc[fm][fn], 0, 0, 0);
            }
            __syncthreads();
        }

        #pragma unroll
        for (int fn = 0; fn < 4; ++fn) {
            const int kp = waveM + fn * 16 + lr;
            const float bias = loadIn(b3, m0 + kp, f32);
            #pragma unroll
            for (int fm = 0; fm < 4; ++fm) {
                const int nb = waveN + fm * 16 + lk * 4;
                uint2 pk;
                pk.x = pk2(acc[fm][fn][0] + bias, acc[fm][fn][1] + bias);
                pk.y = pk2(acc[fm][fn][2] + bias, acc[fm][fn][3] + bias);
                *(uint2*)&Ot[kp * 136 + nb] = pk;
            }
        }
        __syncthreads();
        {
            const int m = t >> 1, half = t & 1;
            const unsigned short* src = &Ot[m * 136 + half * 64];
            unsigned short* dst = TV + ((long)(nTile * 2 + half) * 256 + m0 + m) * 64;
            #pragma unroll
            for (int q = 0; q < 8; ++q)
                *(uint4*)(dst + q * 8) = *(const uint4*)(src + q * 8);
        }
    } else {
        // ---- transA body ----
        unsigned short* T = smem;   // uses 64*66 shorts
        const int bid = blockIdx.x - nV;
        const int nl = bid >> 11;
        const int inner = bid & 2047;
        const unsigned short* A = AuBase + (size_t)nl * 8388608;
        unsigned short* At = AtBase + (size_t)nl * 8388608;
        const int c  = inner >> 5;
        const int gt = (inner >> 2) & 7, pt = inner & 3;
        const int g0 = gt * 64, p0 = pt * 64;

        const int gr = t >> 2, pc = (t & 3) * 16;
        const unsigned int* s32 = (const unsigned int*)(A + (long)c * S_PER_N + (long)(g0 + gr) * 256 + p0 + pc);
        unsigned int* d32 = (unsigned int*)&T[gr * 66 + pc];
        #pragma unroll
        for (int i = 0; i < 8; ++i) d32[i] = s32[i];
        __syncthreads();

        const int pr = t >> 2, gc0 = (t & 3) * 16;
        unsigned int ov[8];
        #pragma unroll
        for (int i = 0; i < 8; ++i) {
            unsigned int lo = T[(gc0 + 2 * i) * 66 + pr];
            unsigned int hi = T[(gc0 + 2 * i + 1) * 66 + pr];
            ov[i] = lo | (hi << 16);
        }
        unsigned int* dst = (unsigned int*)(At + ((long)(p0 + pr) * 64 + c) * 512 + g0 + gc0);
        #pragma unroll
        for (int i = 0; i < 8; ++i) dst[i] = ov[i];
    }
}

// ---------------- umix: global_load_lds staged GEMM; out T_U[(g'*256+p)*64+c] ----------------
__global__ __launch_bounds__(256) void k_umix_mfma(const unsigned short* __restrict__ BtBase,
                                                   const unsigned short* __restrict__ W2b,
                                                   const void* __restrict__ b2,
                                                   const float* __restrict__ flag,
                                                   unsigned short* __restrict__ TUBase) {
    const bool f32 = flag[0] > 0.5f;
    __shared__ __align__(16) unsigned short smem[17408];
    unsigned short* As = smem;
    unsigned short* Bs = smem + 8192;
    unsigned short* Ot = smem;
    const int bid = blockIdx.x;
    const int nl = bid >> 9;
    const int inner = bid & 511;
    const unsigned short* Bt = BtBase + (size_t)nl * 8388608;
    unsigned short* TU = TUBase + (size_t)nl * 8388608;
    const int mTile = inner >> 7;
    const int nTile = inner & 127;
    const int m0 = mTile * 128;
    const int t = threadIdx.x;
    const int lane = t & 63, wid = t >> 6;
    const int waveM = (wid >> 1) * 64, waveN = (wid & 1) * 64;
    const int lr = lane & 15, lk = lane >> 4;
    const int rIn8 = lane >> 3;
    const int swzOff = ((lane & 7) ^ rIn8) << 3;

    f32x4 zero = {0.f, 0.f, 0.f, 0.f};
    f32x4 acc[4][4];
    #pragma unroll
    for (int i = 0; i < 4; ++i)
        #pragma unroll
        for (int j = 0; j < 4; ++j) acc[i][j] = zero;

    for (int kb = 0; kb < 512; kb += 64) {
        #pragma unroll
        for (int call = 0; call < 4; ++call) {
            const int rowBase = call * 32 + wid * 8;
            gld16(W2b + (long)(m0 + rowBase + rIn8) * 512 + kb + swzOff, As + rowBase * 64);
            gld16(Bt + (long)(nTile * 128 + rowBase + rIn8) * 512 + kb + swzOff, Bs + rowBase * 64);
        }
        __syncthreads();
        #pragma unroll
        for (int kk = 0; kk < 2; ++kk) {
            bf16x8 tok[4], wf[4];
            #pragma unroll
            for (int f = 0; f < 4; ++f) {
                tok[f] = fragLd(Bs, waveN + f * 16 + lr, kk * 4 + lk);
                wf[f]  = fragLd(As, waveM + f * 16 + lr, kk * 4 + lk);
            }
            #pragma unroll
            for (int fm = 0; fm < 4; ++fm)
                #pragma unroll
                for (int fn = 0; fn < 4; ++fn)
                    acc[fm][fn] = __builtin_amdgcn_mfma_f32_16x16x32_bf16(tok[fm], wf[fn], acc[fm][fn], 0, 0, 0);
        }
        __syncthreads();
    }

    #pragma unroll
    for (int fn = 0; fn < 4; ++fn) {
        const int gp = waveM + fn * 16 + lr;
        const float bias = loadIn(b2, m0 + gp, f32);
        #pragma unroll
        for (int fm = 0; fm < 4; ++fm) {
            const int nb = waveN + fm * 16 + lk * 4;
            uint2 pk;
            pk.x = pk2(acc[fm][fn][0] + bias, acc[fm][fn][1] + bias);
            pk.y = pk2(acc[fm][fn][2] + bias, acc[fm][fn][3] + bias);
            *(uint2*)&Ot[gp * 136 + nb] = pk;
        }
    }
    __syncthreads();
    {
        const int m = t >> 1, half = t & 1;
        const unsigned short* src = &Ot[m * 136 + half * 64];
        unsigned short* dst = TU + ((long)(m0 + m) * 256 + nTile * 2 + half) * 64;
        #pragma unroll
        for (int q = 0; q < 8; ++q)
            *(uint4*)(dst + q * 8) = *(const uint4*)(src + q * 8);
    }
}

// ---------------- fc2: LDS-free. D[k=64][s-tile=128], K=128; fragments direct ----------------
__global__ __launch_bounds__(256) void k_fc2_mfma(const unsigned short* __restrict__ TUBase,
                                                  const unsigned short* __restrict__ TVBase,
                                                  const unsigned short* __restrict__ W4b,
                                                  const void* __restrict__ b4,
                                                  const float* __restrict__ flag,
                                                  void* __restrict__ out, int nBase) {
    const bool f32 = flag[0] > 0.5f;
    const int bid = blockIdx.x;
    const int nl = bid >> 10;
    const int n = nBase + nl;
    const unsigned short* TU = TUBase + (size_t)nl * 8388608;
    const unsigned short* TV = TVBase + (size_t)nl * 8388608;
    const int s0 = (bid & 1023) * 128;
    const int t = threadIdx.x;
    const int lane = t & 63, wid = t >> 6;
    const int waveN = wid * 32;
    const int lr = lane & 15, lk = lane >> 4;

    long gpv[2];
    #pragma unroll
    for (int fn = 0; fn < 2; ++fn) {
        const int s = s0 + waveN + fn * 16 + lr;
        const int d = s >> 12, h = (s >> 6) & 63, w = s & 63;
        const int g = ((d >> 2) << 6) | ((h >> 3) << 3) | (w >> 3);
        const int p = ((d & 3) << 6) | ((h & 7) << 3) | (w & 7);
        gpv[fn] = (long)g * 256 + p;
    }

    f32x4 zero = {0.f, 0.f, 0.f, 0.f};
    f32x4 acc[4][2];
    #pragma unroll
    for (int i = 0; i < 4; ++i) { acc[i][0] = zero; acc[i][1] = zero; }

    #pragma unroll
    for (int kk = 0; kk < 4; ++kk) {
        const unsigned short* base = (kk < 2) ? TU : TV;
        const int choff = ((kk & 1) * 4 + lk) * 8;
        bf16x8 af[4], bfr[2];
        #pragma unroll
        for (int fm = 0; fm < 4; ++fm)
            af[fm] = *(const bf16x8*)(W4b + (long)(fm * 16 + lr) * 128 + (kk * 4 + lk) * 8);
        #pragma unroll
        for (int fn = 0; fn < 2; ++fn)
            bfr[fn] = *(const bf16x8*)(base + gpv[fn] * 64 + choff);
        #pragma unroll
        for (int fm = 0; fm < 4; ++fm)
            #pragma unroll
            for (int fn = 0; fn < 2; ++fn)
                acc[fm][fn] = __builtin_amdgcn_mfma_f32_16x16x32_bf16(af[fm], bfr[fn], acc[fm][fn], 0, 0, 0);
    }

    #pragma unroll
    for (int fm = 0; fm < 4; ++fm) {
        #pragma unroll
        for (int fn = 0; fn < 2; ++fn) {
            const int scol = s0 + waveN + fn * 16 + lr;
            #pragma unroll
            for (int i = 0; i < 4; ++i) {
                const int k = fm * 16 + lk * 4 + i;
                const float v = acc[fm][fn][i] + loadIn(b4, k, f32);
                storeOut(out, ((long)(n * 64 + k) << 17) + scol, v, f32);
            }
        }
    }
}

extern "C" void kernel_launch(void* const* d_in, const int* in_sizes, int n_in,
                              void* d_out, int out_size, void* d_ws, size_t ws_size,
                              hipStream_t stream) {
    const void* x  = d_in[0];
    const void* W1 = d_in[1];
    const void* b1 = d_in[2];
    const void* W2 = d_in[3];
    const void* b2 = d_in[4];
    const void* W3 = d_in[5];
    const void* b3 = d_in[6];
    const void* W4 = d_in[7];
    const void* b4 = d_in[8];

    float* wsf      = (float*)d_ws;
    float* stats    = wsf;            // 8 floats
    float* flag     = wsf + 8;        // 1 float
    float* partials = wsf + 16;       // 1024 floats
    float* ck       = wsf + 1040;     // 512 floats (ends < 8192 B)

    unsigned short* W2bf = (unsigned short*)((char*)d_ws + 8192);   // 512 KB
    unsigned short* W3bf = W2bf + 512 * 512;                        // 128 KB
    unsigned short* W1bf = W3bf + 256 * 256;                        // 16 KB
    unsigned short* W4bf = W1bf + 128 * 64;                         // 16 KB (ends < 1 MiB)

    const size_t perBuf = (size_t)8388608;                          // shorts per sample buffer (16 MiB)
    const size_t need4  = (1u << 20) + 3ull * 4ull * perBuf * 2ull; // 1 MiB + 192 MiB
    const int cnt = (ws_size >= need4) ? 4 : 1;

    unsigned short* buf1 = (unsigned short*)((char*)d_ws + (1u << 20));
    unsigned short* buf2 = buf1 + (size_t)cnt * perBuf;
    unsigned short* buf3 = buf2 + (size_t)cnt * perBuf;

    hipLaunchKernelGGL(k_detect,      dim3(1),    dim3(256), 0, stream,
                       (const unsigned short*)x, flag);
    hipLaunchKernelGGL(k_stats_prepW, dim3(1536), dim3(256), 0, stream,
                       x, flag, partials, W1, W2, W3, W4, W1bf, W2bf, W3bf, W4bf);
    hipLaunchKernelGGL(k_red_prep,    dim3(1),    dim3(128), 0, stream,
                       partials, stats, W1, b1, flag, ck);

    for (int nBase = 0; nBase < 4; nBase += cnt) {
        hipLaunchKernelGGL(k_fc1_mfma,  dim3(cnt * 512),  dim3(256), 0, stream,
                           x, stats, ck, W1bf, flag, buf2, d_out, nBase);
        hipLaunchKernelGGL(k_tv,        dim3(cnt * 2560), dim3(256), 0, stream,
                           buf2, d_out, W3bf, b3, flag, buf1, buf3, nBase, cnt * 512);
        hipLaunchKernelGGL(k_umix_mfma, dim3(cnt * 512),  dim3(256), 0, stream,
                           buf1, W2bf, b2, flag, buf2);
        hipLaunchKernelGGL(k_fc2_mfma,  dim3(cnt * 1024), dim3(256), 0, stream,
                           buf2, buf3, W4bf, b4, flag, d_out, nBase);
    }
}

// Round 13
// 333.768 us; speedup vs baseline: 1.0113x; 1.0113x over previous
//
#include <hip/hip_runtime.h>
#include <hip/hip_bf16.h>
#include <math.h>

// Geometry (fixed):
//   x: (N=4, C=64, D=32, H=64, W=64); S = 131072 = G*P, G=512, P=256
//   W1 (128,64) b1(128) | W2 (512,512) b2(512) | W3 (256,256) b3(256) | W4 (64,128) b4(64)
// Blocked index: g=(d>>2)*64+(h>>3)*8+(w>>3); p=(d&3)*64+(h&7)*8+(w&7)
//
// Pipeline (batched; cnt=4 if ws fits):
//   detect -> stats+prepW -> red+prep ->
//   fc1:  per-g GEMM, LN folded, sigmoid-GELU -> Au[c][g][p] (buf2), Bv[g][c][p] (d_out n)
//   k_tv: vmix (Bv -> T_V, buf3)  PARALLEL WITH  transA (Au -> At', buf1)
//   umix: At' -> T_U (buf2)
//   fc2:  LDS-free GEMM, swapped operands (D[token][k]) -> float4/uint2 stores

#define S_PER_N 131072
#define CNT_PER_N 8388608.0f

typedef __attribute__((ext_vector_type(8))) short bf16x8;
typedef __attribute__((ext_vector_type(4))) float f32x4;

__device__ __forceinline__ float b2f(unsigned short u) {
    return __uint_as_float(((unsigned int)u) << 16);
}
__device__ __forceinline__ unsigned short f2b(float f) {
    unsigned int i = __float_as_uint(f);
    unsigned int r = i + 0x7FFFu + ((i >> 16) & 1u);
    return (unsigned short)(r >> 16);
}
// pack 2 f32 -> 2 bf16 (RNE) in one instruction
__device__ __forceinline__ unsigned int pk2(float lo, float hi) {
    unsigned int r;
    asm("v_cvt_pk_bf16_f32 %0, %1, %2" : "=v"(r) : "v"(lo), "v"(hi));
    return r;
}
__device__ __forceinline__ float loadIn(const void* p, long i, bool f32) {
    return f32 ? ((const float*)p)[i] : b2f(((const unsigned short*)p)[i]);
}
__device__ __forceinline__ void gld16(const unsigned short* g, unsigned short* l) {
    __builtin_amdgcn_global_load_lds(
        (const __attribute__((address_space(1))) void*)g,
        (__attribute__((address_space(3))) void*)l,
        16, 0, 0);
}
// GELU sigmoid form: x * sigmoid(1.595769x + 0.0713548x^3); max abs err ~3e-4
__device__ __forceinline__ float fast_gelu(float x) {
    const float x2 = x * x;
    const float c = -0.102944f * x2 - 2.3022081f;
    const float q = x * c;
    const float t = __builtin_amdgcn_rcpf(1.0f + __builtin_amdgcn_exp2f(q));
    return x * t;
}

// ---------------- dtype detect ----------------
__global__ void k_detect(const unsigned short* __restrict__ xw, float* __restrict__ flag) {
    __shared__ int sh[256];
    int tid = threadIdx.x;
    int sane = 0;
    for (int i = tid; i < 4096; i += 256) {
        int e = (xw[i] >> 7) & 0xFF;
        sane += (e >= 110 && e <= 130) ? 1 : 0;
    }
    sh[tid] = sane; __syncthreads();
    for (int off = 128; off; off >>= 1) {
        if (tid < off) sh[tid] += sh[tid + off];
        __syncthreads();
    }
    if (tid == 0) flag[0] = (sh[0] >= 3300) ? 0.0f : 1.0f;
}

// ---------------- LN stats (blocks 0..511) + prepW (blocks 512..1535) ----------------
__global__ __launch_bounds__(256) void k_stats_prepW(const void* __restrict__ xp,
                                                     const float* __restrict__ flag,
                                                     float* __restrict__ partials,
                                                     const void* __restrict__ W1,
                                                     const void* __restrict__ W2,
                                                     const void* __restrict__ W3,
                                                     const void* __restrict__ W4,
                                                     unsigned short* __restrict__ W1b,
                                                     unsigned short* __restrict__ W2b,
                                                     unsigned short* __restrict__ W3b,
                                                     unsigned short* __restrict__ W4b) {
    const bool f32 = flag[0] > 0.5f;
    if (blockIdx.x >= 512) {
        const int i = (blockIdx.x - 512) * 256 + threadIdx.x;
        if (i < 512 * 512) W2b[i] = f32 ? f2b(((const float*)W2)[i]) : ((const unsigned short*)W2)[i];
        if (i < 256 * 256) W3b[i] = f32 ? f2b(((const float*)W3)[i]) : ((const unsigned short*)W3)[i];
        if (i < 128 * 64)  W1b[i] = f32 ? f2b(((const float*)W1)[i]) : ((const unsigned short*)W1)[i];
        if (i < 64 * 128)  W4b[i] = f32 ? f2b(((const float*)W4)[i]) : ((const unsigned short*)W4)[i];
        return;
    }
    const int bid = blockIdx.x;
    const long base = (long)bid * 65536;
    float s = 0.0f, sq = 0.0f;
    if (f32) {
        const float4* xv = (const float4*)((const float*)xp + base);
        for (int it = 0; it < 64; ++it) {
            float4 v = xv[it * 256 + threadIdx.x];
            s  += v.x + v.y + v.z + v.w;
            sq += v.x*v.x + v.y*v.y + v.z*v.z + v.w*v.w;
        }
    } else {
        const uint4* xv = (const uint4*)((const unsigned short*)xp + base);
        for (int it = 0; it < 32; ++it) {
            uint4 v = xv[it * 256 + threadIdx.x];
            unsigned int ws4[4] = {v.x, v.y, v.z, v.w};
            #pragma unroll
            for (int q = 0; q < 4; ++q) {
                float f0 = b2f((unsigned short)(ws4[q] & 0xFFFFu));
                float f1 = b2f((unsigned short)(ws4[q] >> 16));
                s += f0 + f1;
                sq += f0 * f0 + f1 * f1;
            }
        }
    }
    __shared__ float ls[256], lq[256];
    ls[threadIdx.x] = s; lq[threadIdx.x] = sq;
    __syncthreads();
    for (int off = 128; off > 0; off >>= 1) {
        if (threadIdx.x < off) {
            ls[threadIdx.x] += ls[threadIdx.x + off];
            lq[threadIdx.x] += lq[threadIdx.x + off];
        }
        __syncthreads();
    }
    if (threadIdx.x == 0) {
        partials[bid * 2 + 0] = ls[0];
        partials[bid * 2 + 1] = lq[0];
    }
}

// ---------------- reduce partials -> stats, then ck (1 block, 128 thr) ----------------
__global__ void k_red_prep(const float* __restrict__ partials, float* __restrict__ stats,
                           const void* __restrict__ W1, const void* __restrict__ b1,
                           const float* __restrict__ flag, float* __restrict__ ck) {
    const int t = threadIdx.x;
    if (t < 4) {
        float s = 0.0f, sq = 0.0f;
        for (int i = 0; i < 128; ++i) {
            s  += partials[(t * 128 + i) * 2 + 0];
            sq += partials[(t * 128 + i) * 2 + 1];
        }
        stats[t * 2 + 0] = s;
        stats[t * 2 + 1] = sq;
    }
    __syncthreads();
    const bool f32 = flag[0] > 0.5f;
    float rs = 0.0f;
    for (int c = 0; c < 64; ++c) rs += loadIn(W1, (long)t * 64 + c, f32);
    const float bb = loadIn(b1, t, f32);
    for (int n = 0; n < 4; ++n) {
        const float mu   = stats[n * 2 + 0] * (1.0f / CNT_PER_N);
        const float m2   = stats[n * 2 + 1] * (1.0f / CNT_PER_N);
        const float rstd = rsqrtf(m2 - mu * mu + 1e-5f);
        ck[n * 128 + t] = bb - rstd * mu * rs;
    }
}

// ---------------- LDS swizzle helper ----------------
__device__ __forceinline__ bf16x8 fragLd(const unsigned short* lds, int r, int c) {
    return *(const bf16x8*)&lds[r * 64 + ((c ^ (r & 7)) << 3)];
}

// ---------------- fc1 (g-tile): D[p=256][j=128], K=64; LN folded, fast GELU ----------------
__global__ __launch_bounds__(256) void k_fc1_mfma(const void* __restrict__ xp,
                                                  const float* __restrict__ stats,
                                                  const float* __restrict__ ck,
                                                  const unsigned short* __restrict__ W1b,
                                                  const float* __restrict__ flag,
                                                  unsigned short* __restrict__ AuBase,
                                                  void* __restrict__ outBase, int nBase) {
    const bool f32 = flag[0] > 0.5f;
    __shared__ __align__(16) unsigned short Bs[256 * 64];   // X^T [p][c]
    const int nwg = gridDim.x;
    const int cpx = nwg >> 3;
    const int work = (blockIdx.x & 7) * cpx + (blockIdx.x >> 3);
    const int nl = work >> 9;
    const int n = nBase + nl;
    const int g = work & 511;
    const int d0 = (g >> 6) * 4, h0 = ((g >> 3) & 7) * 8, w0 = (g & 7) * 8;
    const int t = threadIdx.x;
    const int lane = t & 63, wid = t >> 6;
    const int waveP = wid * 64;
    const int lr = lane & 15, lk = lane >> 4;

    unsigned short* Au = AuBase + (size_t)nl * 8388608;
    unsigned short* Bv = (unsigned short*)((char*)outBase + (size_t)n * 8388608 * (f32 ? 4 : 2));

    {   // stage B: x g-block -> Bs[p][c]
        const int c0 = (t & 31) * 2;
        const int rdh = t >> 5;
        const long cbase = ((long)(n * 64 + c0)) << 17;
        const int ch = c0 >> 3, cof = c0 & 7;
        #pragma unroll
        for (int q = 0; q < 4; ++q) {
            const int dh = rdh * 4 + q;
            const int dp = dh >> 3, hp = dh & 7;
            const long sb = (long)(d0 + dp) * 4096 + (h0 + hp) * 64 + w0;
            const int pbase = dp * 64 + hp * 8;
            if (f32) {
                const float* r0 = (const float*)xp + cbase + sb;
                const float* r1 = r0 + S_PER_N;
                float4 a0 = *(const float4*)r0, a1 = *(const float4*)(r0 + 4);
                float4 b0 = *(const float4*)r1, b1v = *(const float4*)(r1 + 4);
                float ff0[8] = {a0.x, a0.y, a0.z, a0.w, a1.x, a1.y, a1.z, a1.w};
                float ff1[8] = {b0.x, b0.y, b0.z, b0.w, b1v.x, b1v.y, b1v.z, b1v.w};
                #pragma unroll
                for (int j = 0; j < 8; ++j) {
                    const int pj = pbase + j;
                    *(unsigned int*)&Bs[pj * 64 + ((ch ^ (pj & 7)) << 3) + cof] = pk2(ff0[j], ff1[j]);
                }
            } else {
                const unsigned short* r0 = (const unsigned short*)xp + cbase + sb;
                uint4 a = *(const uint4*)r0;
                uint4 b = *(const uint4*)(r0 + S_PER_N);
                const unsigned short* pa = (const unsigned short*)&a;
                const unsigned short* pb = (const unsigned short*)&b;
                #pragma unroll
                for (int j = 0; j < 8; ++j) {
                    const int pj = pbase + j;
                    unsigned int val = (unsigned int)pa[j] | ((unsigned int)pb[j] << 16);
                    *(unsigned int*)&Bs[pj * 64 + ((ch ^ (pj & 7)) << 3) + cof] = val;
                }
            }
        }
    }
    __syncthreads();

    const float mu   = stats[n * 2 + 0] * (1.0f / CNT_PER_N);
    const float m2   = stats[n * 2 + 1] * (1.0f / CNT_PER_N);
    const float rstd = rsqrtf(m2 - mu * mu + 1e-5f);

    #pragma unroll
    for (int half = 0; half < 2; ++half) {
        f32x4 zero = {0.f, 0.f, 0.f, 0.f};
        f32x4 acc[4][4];
        #pragma unroll
        for (int i = 0; i < 4; ++i)
            #pragma unroll
            for (int j = 0; j < 4; ++j) acc[i][j] = zero;

        #pragma unroll
        for (int kk = 0; kk < 2; ++kk) {
            bf16x8 bp[4], aj[4];
            #pragma unroll
            for (int f = 0; f < 4; ++f) {
                bp[f] = fragLd(Bs, waveP + f * 16 + lr, kk * 4 + lk);
                aj[f] = *(const bf16x8*)(W1b + (long)(half * 64 + f * 16 + lr) * 64 + (kk * 4 + lk) * 8);
            }
            #pragma unroll
            for (int fp = 0; fp < 4; ++fp)
                #pragma unroll
                for (int fj = 0; fj < 4; ++fj)
                    acc[fp][fj] = __builtin_amdgcn_mfma_f32_16x16x32_bf16(bp[fp], aj[fj], acc[fp][fj], 0, 0, 0);
        }

        #pragma unroll
        for (int fj = 0; fj < 4; ++fj) {
            const int j = half * 64 + fj * 16 + lr;
            const float ckj = ck[n * 128 + j];
            #pragma unroll
            for (int fp = 0; fp < 4; ++fp) {
                const int pb = waveP + fp * 16 + lk * 4;
                float gg[4];
                #pragma unroll
                for (int i = 0; i < 4; ++i)
                    gg[i] = fast_gelu(acc[fp][fj][i] * rstd + ckj);
                uint2 pk;
                pk.x = pk2(gg[0], gg[1]);
                pk.y = pk2(gg[2], gg[3]);
                if (half == 0) {
                    *(uint2*)&Au[(long)j * S_PER_N + g * 256 + pb] = pk;
                } else {
                    *(uint2*)&Bv[((long)g * 64 + (j - 64)) * 256 + pb] = pk;
                }
            }
        }
    }
}

// ---------------- k_tv: vmix (blocks 0..nV-1) PARALLEL WITH transA (rest) ----------------
__global__ __launch_bounds__(256) void k_tv(const unsigned short* __restrict__ AuBase,
                                            void* __restrict__ outBase,
                                            const unsigned short* __restrict__ W3b,
                                            const void* __restrict__ b3,
                                            const float* __restrict__ flag,
                                            unsigned short* __restrict__ AtBase,
                                            unsigned short* __restrict__ TVBase,
                                            int nBase, int nV) {
    __shared__ __align__(16) unsigned short smem[17408];
    const int t = threadIdx.x;

    if ((int)blockIdx.x < nV) {
        const bool f32 = flag[0] > 0.5f;
        unsigned short* As = smem;
        unsigned short* Bs = smem + 8192;
        unsigned short* Ot = smem;
        const int bid = blockIdx.x;
        const int nl = bid >> 9;
        const int n = nBase + nl;
        const int inner = bid & 511;
        const unsigned short* Bv = (const unsigned short*)((char*)outBase + (size_t)n * 8388608 * (f32 ? 4 : 2));
        unsigned short* TV = TVBase + (size_t)nl * 8388608;
        const int mTile = inner >> 8;
        const int nTile = inner & 255;
        const int m0 = mTile * 128;
        const int lane = t & 63, wid = t >> 6;
        const int waveM = (wid >> 1) * 64, waveN = (wid & 1) * 64;
        const int lr = lane & 15, lk = lane >> 4;
        const int rIn8 = lane >> 3;
        const int swzOff = ((lane & 7) ^ rIn8) << 3;

        f32x4 zero = {0.f, 0.f, 0.f, 0.f};
        f32x4 acc[4][4];
        #pragma unroll
        for (int i = 0; i < 4; ++i)
            #pragma unroll
            for (int j = 0; j < 4; ++j) acc[i][j] = zero;

        for (int kb = 0; kb < 256; kb += 64) {
            #pragma unroll
            for (int call = 0; call < 4; ++call) {
                const int rowBase = call * 32 + wid * 8;
                gld16(W3b + (long)(m0 + rowBase + rIn8) * 256 + kb + swzOff, As + rowBase * 64);
                gld16(Bv + (long)(nTile * 128 + rowBase + rIn8) * 256 + kb + swzOff, Bs + rowBase * 64);
            }
            __syncthreads();
            #pragma unroll
            for (int kk = 0; kk < 2; ++kk) {
                bf16x8 tok[4], wf[4];
                #pragma unroll
                for (int f = 0; f < 4; ++f) {
                    tok[f] = fragLd(Bs, waveN + f * 16 + lr, kk * 4 + lk);
                    wf[f]  = fragLd(As, waveM + f * 16 + lr, kk * 4 + lk);
                }
                #pragma unroll
                for (int fm = 0; fm < 4; ++fm)
                    #pragma unroll
                    for (int fn = 0; fn < 4; ++fn)
                        acc[fm][fn] = __builtin_amdgcn_mfma_f32_16x16x32_bf16(tok[fm], wf[fn], acc[fm][fn], 0, 0, 0);
            }
            __syncthreads();
        }

        #pragma unroll
        for (int fn = 0; fn < 4; ++fn) {
            const int kp = waveM + fn * 16 + lr;
            const float bias = loadIn(b3, m0 + kp, f32);
            #pragma unroll
            for (int fm = 0; fm < 4; ++fm) {
                const int nb = waveN + fm * 16 + lk * 4;
                uint2 pk;
                pk.x = pk2(acc[fm][fn][0] + bias, acc[fm][fn][1] + bias);
                pk.y = pk2(acc[fm][fn][2] + bias, acc[fm][fn][3] + bias);
                *(uint2*)&Ot[kp * 136 + nb] = pk;
            }
        }
        __syncthreads();
        {
            const int m = t >> 1, half = t & 1;
            const unsigned short* src = &Ot[m * 136 + half * 64];
            unsigned short* dst = TV + ((long)(nTile * 2 + half) * 256 + m0 + m) * 64;
            #pragma unroll
            for (int q = 0; q < 8; ++q)
                *(uint4*)(dst + q * 8) = *(const uint4*)(src + q * 8);
        }
    } else {
        unsigned short* T = smem;
        const int bid = blockIdx.x - nV;
        const int nl = bid >> 11;
        const int inner = bid & 2047;
        const unsigned short* A = AuBase + (size_t)nl * 8388608;
        unsigned short* At = AtBase + (size_t)nl * 8388608;
        const int c  = inner >> 5;
        const int gt = (inner >> 2) & 7, pt = inner & 3;
        const int g0 = gt * 64, p0 = pt * 64;

        const int gr = t >> 2, pc = (t & 3) * 16;
        const unsigned int* s32 = (const unsigned int*)(A + (long)c * S_PER_N + (long)(g0 + gr) * 256 + p0 + pc);
        unsigned int* d32 = (unsigned int*)&T[gr * 66 + pc];
        #pragma unroll
        for (int i = 0; i < 8; ++i) d32[i] = s32[i];
        __syncthreads();

        const int pr = t >> 2, gc0 = (t & 3) * 16;
        unsigned int ov[8];
        #pragma unroll
        for (int i = 0; i < 8; ++i) {
            unsigned int lo = T[(gc0 + 2 * i) * 66 + pr];
            unsigned int hi = T[(gc0 + 2 * i + 1) * 66 + pr];
            ov[i] = lo | (hi << 16);
        }
        unsigned int* dst = (unsigned int*)(At + ((long)(p0 + pr) * 64 + c) * 512 + g0 + gc0);
        #pragma unroll
        for (int i = 0; i < 8; ++i) dst[i] = ov[i];
    }
}

// ---------------- umix: global_load_lds staged GEMM; out T_U[(g'*256+p)*64+c] ----------------
__global__ __launch_bounds__(256) void k_umix_mfma(const unsigned short* __restrict__ BtBase,
                                                   const unsigned short* __restrict__ W2b,
                                                   const void* __restrict__ b2,
                                                   const float* __restrict__ flag,
                                                   unsigned short* __restrict__ TUBase) {
    const bool f32 = flag[0] > 0.5f;
    __shared__ __align__(16) unsigned short smem[17408];
    unsigned short* As = smem;
    unsigned short* Bs = smem + 8192;
    unsigned short* Ot = smem;
    const int bid = blockIdx.x;
    const int nl = bid >> 9;
    const int inner = bid & 511;
    const unsigned short* Bt = BtBase + (size_t)nl * 8388608;
    unsigned short* TU = TUBase + (size_t)nl * 8388608;
    const int mTile = inner >> 7;
    const int nTile = inner & 127;
    const int m0 = mTile * 128;
    const int t = threadIdx.x;
    const int lane = t & 63, wid = t >> 6;
    const int waveM = (wid >> 1) * 64, waveN = (wid & 1) * 64;
    const int lr = lane & 15, lk = lane >> 4;
    const int rIn8 = lane >> 3;
    const int swzOff = ((lane & 7) ^ rIn8) << 3;

    f32x4 zero = {0.f, 0.f, 0.f, 0.f};
    f32x4 acc[4][4];
    #pragma unroll
    for (int i = 0; i < 4; ++i)
        #pragma unroll
        for (int j = 0; j < 4; ++j) acc[i][j] = zero;

    for (int kb = 0; kb < 512; kb += 64) {
        #pragma unroll
        for (int call = 0; call < 4; ++call) {
            const int rowBase = call * 32 + wid * 8;
            gld16(W2b + (long)(m0 + rowBase + rIn8) * 512 + kb + swzOff, As + rowBase * 64);
            gld16(Bt + (long)(nTile * 128 + rowBase + rIn8) * 512 + kb + swzOff, Bs + rowBase * 64);
        }
        __syncthreads();
        #pragma unroll
        for (int kk = 0; kk < 2; ++kk) {
            bf16x8 tok[4], wf[4];
            #pragma unroll
            for (int f = 0; f < 4; ++f) {
                tok[f] = fragLd(Bs, waveN + f * 16 + lr, kk * 4 + lk);
                wf[f]  = fragLd(As, waveM + f * 16 + lr, kk * 4 + lk);
            }
            #pragma unroll
            for (int fm = 0; fm < 4; ++fm)
                #pragma unroll
                for (int fn = 0; fn < 4; ++fn)
                    acc[fm][fn] = __builtin_amdgcn_mfma_f32_16x16x32_bf16(tok[fm], wf[fn], acc[fm][fn], 0, 0, 0);
        }
        __syncthreads();
    }

    #pragma unroll
    for (int fn = 0; fn < 4; ++fn) {
        const int gp = waveM + fn * 16 + lr;
        const float bias = loadIn(b2, m0 + gp, f32);
        #pragma unroll
        for (int fm = 0; fm < 4; ++fm) {
            const int nb = waveN + fm * 16 + lk * 4;
            uint2 pk;
            pk.x = pk2(acc[fm][fn][0] + bias, acc[fm][fn][1] + bias);
            pk.y = pk2(acc[fm][fn][2] + bias, acc[fm][fn][3] + bias);
            *(uint2*)&Ot[gp * 136 + nb] = pk;
        }
    }
    __syncthreads();
    {
        const int m = t >> 1, half = t & 1;
        const unsigned short* src = &Ot[m * 136 + half * 64];
        unsigned short* dst = TU + ((long)(m0 + m) * 256 + nTile * 2 + half) * 64;
        #pragma unroll
        for (int q = 0; q < 8; ++q)
            *(uint4*)(dst + q * 8) = *(const uint4*)(src + q * 8);
    }
}

// ---------------- fc2: LDS-free, swapped operands. D[token][k]; float4/uint2 stores ----------------
__global__ __launch_bounds__(256) void k_fc2_mfma(const unsigned short* __restrict__ TUBase,
                                                  const unsigned short* __restrict__ TVBase,
                                                  const unsigned short* __restrict__ W4b,
                                                  const void* __restrict__ b4,
                                                  const float* __restrict__ flag,
                                                  void* __restrict__ out, int nBase) {
    const bool f32 = flag[0] > 0.5f;
    const int bid = blockIdx.x;
    const int nl = bid >> 10;
    const int n = nBase + nl;
    const unsigned short* TU = TUBase + (size_t)nl * 8388608;
    const unsigned short* TV = TVBase + (size_t)nl * 8388608;
    const int s0 = (bid & 1023) * 128;
    const int t = threadIdx.x;
    const int lane = t & 63, wid = t >> 6;
    const int lr = lane & 15, lk = lane >> 4;
    const int tokBase = s0 + wid * 32;      // wave's 32 tokens

    // load-side token row offsets (token = tokBase + ft*16 + lr)
    long gpv[2];
    #pragma unroll
    for (int ft = 0; ft < 2; ++ft) {
        const int s = tokBase + ft * 16 + lr;
        const int d = s >> 12, h = (s >> 6) & 63, w = s & 63;
        const int g = ((d >> 2) << 6) | ((h >> 3) << 3) | (w >> 3);
        const int p = ((d & 3) << 6) | ((h & 7) << 3) | (w & 7);
        gpv[ft] = (long)g * 256 + p;
    }

    f32x4 zero = {0.f, 0.f, 0.f, 0.f};
    f32x4 acc[2][4];
    #pragma unroll
    for (int i = 0; i < 2; ++i)
        #pragma unroll
        for (int j = 0; j < 4; ++j) acc[i][j] = zero;

    #pragma unroll
    for (int kk = 0; kk < 4; ++kk) {
        const unsigned short* base = (kk < 2) ? TU : TV;
        const int choff = ((kk & 1) * 4 + lk) * 8;
        bf16x8 ta[2], wb[4];
        #pragma unroll
        for (int ft = 0; ft < 2; ++ft)
            ta[ft] = *(const bf16x8*)(base + gpv[ft] * 64 + choff);
        #pragma unroll
        for (int fk = 0; fk < 4; ++fk)
            wb[fk] = *(const bf16x8*)(W4b + (long)(fk * 16 + lr) * 128 + (kk * 4 + lk) * 8);
        #pragma unroll
        for (int ft = 0; ft < 2; ++ft)
            #pragma unroll
            for (int fk = 0; fk < 4; ++fk)
                acc[ft][fk] = __builtin_amdgcn_mfma_f32_16x16x32_bf16(ta[ft], wb[fk], acc[ft][fk], 0, 0, 0);
    }

    // stores: D rows = tokens (4 consecutive per lane), cols = k = fk*16+lr
    float bias[4];
    #pragma unroll
    for (int fk = 0; fk < 4; ++fk) bias[fk] = loadIn(b4, fk * 16 + lr, f32);

    #pragma unroll
    for (int ft = 0; ft < 2; ++ft) {
        const int tok0 = tokBase + ft * 16 + lk * 4;
        #pragma unroll
        for (int fk = 0; fk < 4; ++fk) {
            const int k = fk * 16 + lr;
            const long off = ((long)(n * 64 + k) << 17) + tok0;
            if (f32) {
                float4 v = {acc[ft][fk][0] + bias[fk], acc[ft][fk][1] + bias[fk],
                            acc[ft][fk][2] + bias[fk], acc[ft][fk][3] + bias[fk]};
                *(float4*)((float*)out + off) = v;
            } else {
                uint2 pk;
                pk.x = pk2(acc[ft][fk][0] + bias[fk], acc[ft][fk][1] + bias[fk]);
                pk.y = pk2(acc[ft][fk][2] + bias[fk], acc[ft][fk][3] + bias[fk]);
                *(uint2*)((unsigned short*)out + off) = pk;
            }
        }
    }
}

extern "C" void kernel_launch(void* const* d_in, const int* in_sizes, int n_in,
                              void* d_out, int out_size, void* d_ws, size_t ws_size,
                              hipStream_t stream) {
    const void* x  = d_in[0];
    const void* W1 = d_in[1];
    const void* b1 = d_in[2];
    const void* W2 = d_in[3];
    const void* b2 = d_in[4];
    const void* W3 = d_in[5];
    const void* b3 = d_in[6];
    const void* W4 = d_in[7];
    const void* b4 = d_in[8];

    float* wsf      = (float*)d_ws;
    float* stats    = wsf;            // 8 floats
    float* flag     = wsf + 8;        // 1 float
    float* partials = wsf + 16;       // 1024 floats
    float* ck       = wsf + 1040;     // 512 floats (ends < 8192 B)

    unsigned short* W2bf = (unsigned short*)((char*)d_ws + 8192);   // 512 KB
    unsigned short* W3bf = W2bf + 512 * 512;                        // 128 KB
    unsigned short* W1bf = W3bf + 256 * 256;                        // 16 KB
    unsigned short* W4bf = W1bf + 128 * 64;                         // 16 KB (ends < 1 MiB)

    const size_t perBuf = (size_t)8388608;                          // shorts per sample buffer (16 MiB)
    const size_t need4  = (1u << 20) + 3ull * 4ull * perBuf * 2ull; // 1 MiB + 192 MiB
    const int cnt = (ws_size >= need4) ? 4 : 1;

    unsigned short* buf1 = (unsigned short*)((char*)d_ws + (1u << 20));
    unsigned short* buf2 = buf1 + (size_t)cnt * perBuf;
    unsigned short* buf3 = buf2 + (size_t)cnt * perBuf;

    hipLaunchKernelGGL(k_detect,      dim3(1),    dim3(256), 0, stream,
                       (const unsigned short*)x, flag);
    hipLaunchKernelGGL(k_stats_prepW, dim3(1536), dim3(256), 0, stream,
                       x, flag, partials, W1, W2, W3, W4, W1bf, W2bf, W3bf, W4bf);
    hipLaunchKernelGGL(k_red_prep,    dim3(1),    dim3(128), 0, stream,
                       partials, stats, W1, b1, flag, ck);

    for (int nBase = 0; nBase < 4; nBase += cnt) {
        hipLaunchKernelGGL(k_fc1_mfma,  dim3(cnt * 512),  dim3(256), 0, stream,
                           x, stats, ck, W1bf, flag, buf2, d_out, nBase);
        hipLaunchKernelGGL(k_tv,        dim3(cnt * 2560), dim3(256), 0, stream,
                           buf2, d_out, W3bf, b3, flag, buf1, buf3, nBase, cnt * 512);
        hipLaunchKernelGGL(k_umix_mfma, dim3(cnt * 512),  dim3(256), 0, stream,
                           buf1, W2bf, b2, flag, buf2);
        hipLaunchKernelGGL(k_fc2_mfma,  dim3(cnt * 1024), dim3(256), 0, stream,
                           buf2, buf3, W4bf, b4, flag, d_out, nBase);
    }
}